// Round 5
// baseline (289.726 us; speedup 1.0000x reference)
//
#include <hip/hip_runtime.h>
#include <hip/hip_fp16.h>
#include <math.h>

#define BATCH 8
#define H 480
#define W 640
#define HW (H * W)
#define NPIX ((size_t)BATCH * HW)

// ---- prop geometry: S=8 steps per launch, 2 launches ----
#define S 8
#define TX 112                // output tile width
#define TY 48                 // output tile height
#define RXr 128               // region cols (TX + 2S)
#define RYr 64                // region rows (TY + 2S)
#define NTHR 512              // 8 waves; 32 patch-cols x 16 patch-rows of 4x4
#define LROW 136              // LDS row stride: 4 pad | 128 | 4 pad
#define LROWS 66              // 1 pad | 64 | 1 pad

__device__ __forceinline__ unsigned pk2(float a, float b) {
    unsigned lo = __half_as_ushort(__float2half_rn(a));
    unsigned hi = __half_as_ushort(__float2half_rn(b));
    return lo | (hi << 16);
}
__device__ __forceinline__ float lo2f(unsigned u) {
    return __half2float(__ushort_as_half((unsigned short)(u & 0xffffu)));
}
__device__ __forceinline__ float hi2f(unsigned u) {
    return __half2float(__ushort_as_half((unsigned short)(u >> 16)));
}

// softmax + mask fold; planar fp16-pair output (5 u32 planes):
// plane0={w0,w1} plane1={w2,w3} plane2={w4,w5} plane3={w6,w7} plane4={w8,bias}
__global__ __launch_bounds__(256) void fuse_kernel(
    const float* __restrict__ guided,   // (B,9,H,W)
    const float* __restrict__ x,        // (B,1,H,W)
    const float* __restrict__ sparse,   // (B,1,H,W)
    unsigned* __restrict__ wpl)         // 5 * NPIX u32
{
    const int j = blockIdx.x * 256 + threadIdx.x;     // quad index in image
    const int b = blockIdx.z;
    const size_t p4 = (size_t)b * HW + 4 * (size_t)j;
    const size_t gb = (size_t)b * 9 * HW + 4 * (size_t)j;

    float4 g[9];
#pragma unroll
    for (int k = 0; k < 9; ++k)
        g[k] = *(const float4*)(guided + gb + (size_t)k * HW);
    const float4 xq = *(const float4*)(x + p4);
    const float4 sq = *(const float4*)(sparse + p4);
    const float* xp = (const float*)&xq;
    const float* sp = (const float*)&sq;

    unsigned o0[4], o1[4], o2[4], o3[4], o4[4];
#pragma unroll
    for (int cc = 0; cc < 4; ++cc) {
        float w[9];
        float m = -INFINITY;
#pragma unroll
        for (int k = 0; k < 9; ++k) {
            w[k] = ((const float*)&g[k])[cc];
            m = fmaxf(m, w[k]);
        }
        float ssum = 0.0f;
#pragma unroll
        for (int k = 0; k < 9; ++k) { w[k] = __expf(w[k] - m); ssum += w[k]; }
        const float mask = (sp[cc] > 0.0f) ? 1.0f : 0.0f;
        const float scale = (1.0f - mask) / ssum;
        o0[cc] = pk2(w[0] * scale, w[1] * scale);
        o1[cc] = pk2(w[2] * scale, w[3] * scale);
        o2[cc] = pk2(w[4] * scale, w[5] * scale);
        o3[cc] = pk2(w[6] * scale, w[7] * scale);
        o4[cc] = pk2(w[8] * scale, mask * xp[cc]);
    }
    *(uint4*)(wpl + 0 * NPIX + p4) = make_uint4(o0[0], o0[1], o0[2], o0[3]);
    *(uint4*)(wpl + 1 * NPIX + p4) = make_uint4(o1[0], o1[1], o1[2], o1[3]);
    *(uint4*)(wpl + 2 * NPIX + p4) = make_uint4(o2[0], o2[1], o2[2], o2[3]);
    *(uint4*)(wpl + 3 * NPIX + p4) = make_uint4(o3[0], o3[1], o3[2], o3[3]);
    *(uint4*)(wpl + 4 * NPIX + p4) = make_uint4(o4[0], o4[1], o4[2], o4[3]);
}

__device__ __forceinline__ float px9(unsigned u01, unsigned u23, unsigned u45,
                                     unsigned u67, unsigned u8b,
                                     float t0, float t1, float t2,
                                     float m0, float m1, float m2,
                                     float b0, float b1, float b2) {
    float a = hi2f(u8b);                     // bias
    a = fmaf(lo2f(u01), t0, a);
    a = fmaf(hi2f(u01), t1, a);
    a = fmaf(lo2f(u23), t2, a);
    a = fmaf(hi2f(u23), m0, a);
    a = fmaf(lo2f(u45), m1, a);
    a = fmaf(hi2f(u45), m2, a);
    a = fmaf(lo2f(u67), b0, a);
    a = fmaf(hi2f(u67), b1, a);
    a = fmaf(lo2f(u8b), b2, a);
    return a;
}

// 8 fused Jacobi steps; 4x4 px patch per thread; weights in registers;
// double-buffered LDS region; no write guards (stale rim never read by
// valid pixels; out-of-image pixels have w=0,bias=0 -> stay exactly 0).
__global__ __launch_bounds__(NTHR, 4) void prop8_kernel(
    const float* __restrict__ xin,      // (B,H,W)
    const unsigned* __restrict__ wpl,   // 5 planes
    float* __restrict__ xout)           // (B,H,W)
{
    __shared__ __align__(16) float xs[2][LROWS][LROW];

    const int tid = threadIdx.x;
    const int c0 = (tid & 31) * 4;      // region col of patch left
    const int r0 = (tid >> 5) * 4;      // region row of patch top
    const int b = blockIdx.z;
    const int bx0 = blockIdx.x * TX, by0 = blockIdx.y * TY;
    const int gx0 = bx0 - S, gy0 = by0 - S;
    const size_t ob = (size_t)b * HW;

    // zero both buffers (incl. pads)
    for (int i = tid; i < 2 * LROWS * LROW / 4; i += NTHR)
        ((float4*)xs)[i] = make_float4(0.f, 0.f, 0.f, 0.f);
    __syncthreads();

    // fill buffer0 interior with x region; load own-patch weights to regs
    uint4 q01[4], q23[4], q45[4], q67[4], q8b[4];
    const int gxc = gx0 + c0;
    const bool xok = (gxc >= 0) && (gxc < W);
#pragma unroll
    for (int i = 0; i < 4; ++i) {
        const int gy = gy0 + r0 + i;
        const uint4 z = make_uint4(0u, 0u, 0u, 0u);
        float4 xv = make_float4(0.f, 0.f, 0.f, 0.f);
        q01[i] = z; q23[i] = z; q45[i] = z; q67[i] = z; q8b[i] = z;
        if (xok && gy >= 0 && gy < H) {
            const size_t p = ob + (size_t)gy * W + gxc;
            xv     = *(const float4*)(xin + p);
            q01[i] = *(const uint4*)(wpl + 0 * NPIX + p);
            q23[i] = *(const uint4*)(wpl + 1 * NPIX + p);
            q45[i] = *(const uint4*)(wpl + 2 * NPIX + p);
            q67[i] = *(const uint4*)(wpl + 3 * NPIX + p);
            q8b[i] = *(const uint4*)(wpl + 4 * NPIX + p);
        }
        *(float4*)&xs[0][1 + r0 + i][4 + c0] = xv;
    }
    __syncthreads();

#define LOADROW(dst, rdbuf, lr) do {                                   \
        const float* rp_ = &rdbuf[lr][4 + c0];                         \
        dst[0] = rp_[-1];                                              \
        const float4 m_ = *(const float4*)rp_;                         \
        dst[1] = m_.x; dst[2] = m_.y; dst[3] = m_.z; dst[4] = m_.w;    \
        dst[5] = rp_[4];                                               \
    } while (0)

#define COMPROW(i, T, M, Bo) do {                                      \
        float4 o_;                                                     \
        o_.x = px9(q01[i].x, q23[i].x, q45[i].x, q67[i].x, q8b[i].x,   \
                   T[0], T[1], T[2], M[0], M[1], M[2], Bo[0], Bo[1], Bo[2]); \
        o_.y = px9(q01[i].y, q23[i].y, q45[i].y, q67[i].y, q8b[i].y,   \
                   T[1], T[2], T[3], M[1], M[2], M[3], Bo[1], Bo[2], Bo[3]); \
        o_.z = px9(q01[i].z, q23[i].z, q45[i].z, q67[i].z, q8b[i].z,   \
                   T[2], T[3], T[4], M[2], M[3], M[4], Bo[2], Bo[3], Bo[4]); \
        o_.w = px9(q01[i].w, q23[i].w, q45[i].w, q67[i].w, q8b[i].w,   \
                   T[3], T[4], T[5], M[3], M[4], M[5], Bo[3], Bo[4], Bo[5]); \
        *(float4*)&wr[1 + r0 + (i)][4 + c0] = o_;                      \
    } while (0)

    float Ar[6], Br[6], Cr[6];
    for (int t = 1; t <= S; ++t) {
        const float (*rd)[LROW] = xs[(t + 1) & 1];
        float (*wr)[LROW] = xs[t & 1];
        LOADROW(Ar, rd, r0);        // region row r0-1 (lds row r0)
        LOADROW(Br, rd, r0 + 1);
        LOADROW(Cr, rd, r0 + 2);
        COMPROW(0, Ar, Br, Cr);
        LOADROW(Ar, rd, r0 + 3);
        COMPROW(1, Br, Cr, Ar);
        LOADROW(Br, rd, r0 + 4);
        COMPROW(2, Cr, Ar, Br);
        LOADROW(Cr, rd, r0 + 5);
        COMPROW(3, Ar, Br, Cr);
        __syncthreads();
    }

    // result is in buffer 0; copy out tile (coalesced, guarded for ragged x)
    const int col = tid & 127;
    const int rr4 = tid >> 7;
    if (col < TX) {
        const int gx = bx0 + col;
        if (gx < W) {
#pragma unroll
            for (int i = 0; i < TY / 4; ++i) {
                const int row = i * 4 + rr4;
                xout[ob + (size_t)(by0 + row) * W + gx] =
                    xs[0][1 + S + row][4 + S + col];
            }
        }
    }
#undef LOADROW
#undef COMPROW
}

extern "C" void kernel_launch(void* const* d_in, const int* in_sizes, int n_in,
                              void* d_out, int out_size, void* d_ws, size_t ws_size,
                              hipStream_t stream) {
    const float* guided = (const float*)d_in[0];
    const float* x      = (const float*)d_in[1];
    const float* sparse = (const float*)d_in[2];
    float* out = (float*)d_out;

    // ws: 5 weight planes (u32/px) | xA (f32/px)  => 24 B/px = 59 MB
    unsigned* wpl = (unsigned*)d_ws;
    float*    xA  = (float*)(wpl + 5 * NPIX);

    {
        dim3 blk(256, 1, 1);
        dim3 grd(HW / 4 / 256, 1, BATCH);    // 300 x 1 x 8
        fuse_kernel<<<grd, blk, 0, stream>>>(guided, x, sparse, wpl);
    }
    {
        dim3 blk(NTHR, 1, 1);
        dim3 grd((W + TX - 1) / TX, H / TY, BATCH);   // 6 x 10 x 8 = 480
        prop8_kernel<<<grd, blk, 0, stream>>>(x,  wpl, xA);
        prop8_kernel<<<grd, blk, 0, stream>>>(xA, wpl, out);
    }
}

// Round 6
// 105.464 us; speedup vs baseline: 2.7472x; 2.7472x over previous
//
#include <hip/hip_runtime.h>
#include <hip/hip_fp16.h>
#include <math.h>

#define BATCH 8
#define H 480
#define W 640
#define HW (H * W)
#define NPIX ((size_t)BATCH * HW)

// ---- prop geometry: S=8 steps per launch, 2 launches ----
#define PS 8                  // fused steps
#define PTX 112               // output tile width
#define PTY 32                // output tile height
#define PRX 128               // region cols = PTX + 2*PS
#define PRY 48                // region rows = PTY + 2*PS
#define PLSTR 130             // LDS row stride: 1 pad | 128 | 1 pad
#define PNT 768               // threads: 128 cols x 6 strips
#define RPT 8                 // rows per thread (PRY / 6)

__device__ __forceinline__ unsigned pk2(float a, float b) {
    unsigned lo = __half_as_ushort(__float2half_rn(a));
    unsigned hi = __half_as_ushort(__float2half_rn(b));
    return lo | (hi << 16);
}
__device__ __forceinline__ float lo2f(unsigned u) {
    return __half2float(__ushort_as_half((unsigned short)(u & 0xffffu)));
}
__device__ __forceinline__ float hi2f(unsigned u) {
    return __half2float(__ushort_as_half((unsigned short)(u >> 16)));
}

// softmax + mask fold; planar fp16-pair output (5 u32 planes):
// plane0={w0,w1} plane1={w2,w3} plane2={w4,w5} plane3={w6,w7} plane4={w8,bias}
__global__ __launch_bounds__(256) void fuse_kernel(
    const float* __restrict__ guided,   // (B,9,H,W)
    const float* __restrict__ x,        // (B,1,H,W)
    const float* __restrict__ sparse,   // (B,1,H,W)
    unsigned* __restrict__ wpl)         // 5 * NPIX u32
{
    const int j = blockIdx.x * 256 + threadIdx.x;     // quad index in image
    const int b = blockIdx.z;
    const size_t p4 = (size_t)b * HW + 4 * (size_t)j;
    const size_t gb = (size_t)b * 9 * HW + 4 * (size_t)j;

    float4 g[9];
#pragma unroll
    for (int k = 0; k < 9; ++k)
        g[k] = *(const float4*)(guided + gb + (size_t)k * HW);
    const float4 xq = *(const float4*)(x + p4);
    const float4 sq = *(const float4*)(sparse + p4);
    const float* xp = (const float*)&xq;
    const float* sp = (const float*)&sq;

    unsigned o0[4], o1[4], o2[4], o3[4], o4[4];
#pragma unroll
    for (int cc = 0; cc < 4; ++cc) {
        float w[9];
        float m = -INFINITY;
#pragma unroll
        for (int k = 0; k < 9; ++k) {
            w[k] = ((const float*)&g[k])[cc];
            m = fmaxf(m, w[k]);
        }
        float ssum = 0.0f;
#pragma unroll
        for (int k = 0; k < 9; ++k) { w[k] = __expf(w[k] - m); ssum += w[k]; }
        const float mask = (sp[cc] > 0.0f) ? 1.0f : 0.0f;
        const float scale = (1.0f - mask) / ssum;
        o0[cc] = pk2(w[0] * scale, w[1] * scale);
        o1[cc] = pk2(w[2] * scale, w[3] * scale);
        o2[cc] = pk2(w[4] * scale, w[5] * scale);
        o3[cc] = pk2(w[6] * scale, w[7] * scale);
        o4[cc] = pk2(w[8] * scale, mask * xp[cc]);
    }
    *(uint4*)(wpl + 0 * NPIX + p4) = make_uint4(o0[0], o0[1], o0[2], o0[3]);
    *(uint4*)(wpl + 1 * NPIX + p4) = make_uint4(o1[0], o1[1], o1[2], o1[3]);
    *(uint4*)(wpl + 2 * NPIX + p4) = make_uint4(o2[0], o2[1], o2[2], o2[3]);
    *(uint4*)(wpl + 3 * NPIX + p4) = make_uint4(o3[0], o3[1], o3[2], o3[3]);
    *(uint4*)(wpl + 4 * NPIX + p4) = make_uint4(o4[0], o4[1], o4[2], o4[3]);
}

// 8 fused Jacobi steps. Lane = region column (stride-1 LDS addressing,
// conflict-free), 8 rows per thread, weights in ~40 VGPRs, double-buffered
// LDS (one barrier per step). Rim rows/cols use clamped/pad reads: their
// values go stale but are provably never read by pixels that still need
// correctness (trapezoid property). Out-of-image pixels have w=0, bias=0
// so they stay exactly 0 (= zero-padding semantics).
__global__ __launch_bounds__(PNT) void prop8_kernel(
    const float* __restrict__ xin,      // (B,H,W)
    const unsigned* __restrict__ wpl,   // 5 planes
    float* __restrict__ xout)           // (B,H,W)
{
    __shared__ float xs[2][PRY][PLSTR];   // 49,920 B

    const int tid = threadIdx.x;
    const int c  = tid & 127;            // region col
    const int s  = tid >> 7;             // strip (0..5)
    const int r0 = s * RPT;              // first region row of strip
    const int b  = blockIdx.z;
    const int bx0 = blockIdx.x * PTX, by0 = blockIdx.y * PTY;
    const int gx0 = bx0 - PS, gy0 = by0 - PS;
    const size_t ob = (size_t)b * HW;

    // zero the pad columns of BOTH buffers (never written afterwards)
    if (tid < 2 * PRY * 2) {
        const int bf = tid / (PRY * 2), rem = tid % (PRY * 2);
        xs[bf][rem >> 1][(rem & 1) * (PLSTR - 1)] = 0.0f;
    }
    // fill buffer0 interior with x region (zeros outside image)
    for (int i = tid; i < PRY * PRX; i += PNT) {     // 6144 = 8 * 768
        const int r = i >> 7, cc = i & 127;
        const int gy = gy0 + r, gx = gx0 + cc;
        float v = 0.0f;
        if (gy >= 0 && gy < H && gx >= 0 && gx < W)
            v = xin[ob + (size_t)gy * W + gx];
        xs[0][r][1 + cc] = v;
    }

    // own-column weights -> registers (40 u32), coalesced planar loads
    unsigned q0[RPT], q1[RPT], q2[RPT], q3[RPT], q4[RPT];
    {
        const int gx = gx0 + c;
        const bool xok = (gx >= 0) && (gx < W);
#pragma unroll
        for (int i = 0; i < RPT; ++i) {
            const int gy = gy0 + r0 + i;
            if (xok && gy >= 0 && gy < H) {
                const size_t p = ob + (size_t)gy * W + gx;
                q0[i] = wpl[0 * NPIX + p];
                q1[i] = wpl[1 * NPIX + p];
                q2[i] = wpl[2 * NPIX + p];
                q3[i] = wpl[3 * NPIX + p];
                q4[i] = wpl[4 * NPIX + p];
            } else {
                q0[i] = 0u; q1[i] = 0u; q2[i] = 0u; q3[i] = 0u; q4[i] = 0u;
            }
        }
    }
    __syncthreads();

    const int rtop = (s == 0) ? 0 : (r0 - 1);                 // clamp at rim
    const int rbot = (r0 + RPT > PRY - 1) ? (PRY - 1) : (r0 + RPT);

    for (int t = 0; t < PS; ++t) {
        const float (*rd)[PLSTR] = xs[t & 1];
        float (*wr)[PLSTR] = xs[(t + 1) & 1];
        // 3-float window sliding down the strip; stride-1 lane addressing
        float t0 = rd[rtop][c], t1 = rd[rtop][c + 1], t2 = rd[rtop][c + 2];
        float m0 = rd[r0][c],   m1 = rd[r0][c + 1],   m2 = rd[r0][c + 2];
#pragma unroll
        for (int i = 0; i < RPT; ++i) {
            const int rb = (i == RPT - 1) ? rbot : (r0 + i + 1);
            const float b0 = rd[rb][c], b1 = rd[rb][c + 1], b2 = rd[rb][c + 2];
            float a = hi2f(q4[i]);                  // bias
            a = fmaf(lo2f(q0[i]), t0, a);
            a = fmaf(hi2f(q0[i]), t1, a);
            a = fmaf(lo2f(q1[i]), t2, a);
            a = fmaf(hi2f(q1[i]), m0, a);
            a = fmaf(lo2f(q2[i]), m1, a);
            a = fmaf(hi2f(q2[i]), m2, a);
            a = fmaf(lo2f(q3[i]), b0, a);
            a = fmaf(hi2f(q3[i]), b1, a);
            a = fmaf(lo2f(q4[i]), b2, a);
            wr[r0 + i][1 + c] = a;
            t0 = m0; t1 = m1; t2 = m2;
            m0 = b0; m1 = b1; m2 = b2;
        }
        __syncthreads();        // wr complete before it becomes rd
    }

    // after 8 steps (even), final values are in buffer 0; write tile out
    for (int i = tid; i < PTX * PTY; i += PNT) {
        const int r = i / PTX, cc = i % PTX;
        const int gx = bx0 + cc;
        if (gx < W)
            xout[ob + (size_t)(by0 + r) * W + gx] = xs[0][PS + r][1 + PS + cc];
    }
}

extern "C" void kernel_launch(void* const* d_in, const int* in_sizes, int n_in,
                              void* d_out, int out_size, void* d_ws, size_t ws_size,
                              hipStream_t stream) {
    const float* guided = (const float*)d_in[0];
    const float* x      = (const float*)d_in[1];
    const float* sparse = (const float*)d_in[2];
    float* out = (float*)d_out;

    // ws: 5 weight planes (u32/px) | xA (f32/px) => 24 B/px ≈ 59 MB
    unsigned* wpl = (unsigned*)d_ws;
    float*    xA  = (float*)(wpl + 5 * NPIX);

    {
        dim3 blk(256, 1, 1);
        dim3 grd(HW / 4 / 256, 1, BATCH);    // 300 x 1 x 8
        fuse_kernel<<<grd, blk, 0, stream>>>(guided, x, sparse, wpl);
    }
    {
        dim3 blk(PNT, 1, 1);
        dim3 grd((W + PTX - 1) / PTX, H / PTY, BATCH);   // 6 x 15 x 8 = 720
        prop8_kernel<<<grd, blk, 0, stream>>>(x,  wpl, xA);
        prop8_kernel<<<grd, blk, 0, stream>>>(xA, wpl, out);
    }
}